// Round 1
// baseline (352.895 us; speedup 1.0000x reference)
//
#include <hip/hip_runtime.h>
#include <hip/hip_fp16.h>
#include <cstdint>

// Problem constants (setup_inputs: B=8, H=W=512, num_erosions=2)
static constexpr int B = 8;
static constexpr int H = 512;
static constexpr int W = 512;
static constexpr int HW = H * W;
static constexpr int NPIX = B * HW;
static constexpr int NB1 = 1024;  // blocks for cross_max partials
static constexpr int NBD = 1024;  // blocks per dil_diff level

// 10*log2(e): sigmoid(10*z) = 1/(1+2^(-CC*z))
static constexpr float CC = 14.4269504088896f;

// ---------------- helpers ----------------------------------------------------
// Raw v_exp_f32/v_rcp_f32 via builtins (R4: ocml exp = ~12 inst). No
// multi-block atomics (R5: same-line atomic chain serializes device-wide).
// Straight-line sigmoids (R3: wave-vote branches killed ILP). R11 mega
// co-scheduling regressed (VGPR/occupancy) — R10 structure retained.
// R12: issue dropped 8% with no time change -> cp stall-bound at ~41% occ;
// R13 requests 8 waves/EU residency.
// R14: CP planes interleaved per pixel ([...][x][plane], 4 halves = 8B).
//   Old plane-strided 2B half stores caused 8.7x write amplification
//   (WRITE_SIZE 419MB vs 48MB algorithmic: partial-line RMW + cross-XCD
//   line sharing). Interleaved: one 8B store/thread = full 128B lines per
//   16-lane row; dil_diff reads become 8B loads (4x fewer VMEM instrs).
__device__ __forceinline__ float rcpf(float x) { return __builtin_amdgcn_rcpf(x); }
__device__ __forceinline__ float exp2f_n(float x) { return __builtin_amdgcn_exp2f(x); }
__device__ __forceinline__ float endsig(float nc) {
    return rcpf(1.0f + exp2f_n(fmaf(nc, CC, -CC)));
}
__device__ __forceinline__ float sig_cp(float x) {  // sigmoid(10(x-0.5))
    return rcpf(1.0f + exp2f_n(fmaf(x, -CC, 0.5f * CC)));
}
__device__ __forceinline__ float sig_er(float r) {  // sigmoid(10(r-0.7))
    return rcpf(1.0f + exp2f_n(fmaf(r, -CC, 0.7f * CC)));
}
// Shared-exp complement pair (R12): u_d=2^(CC*nc-CC), u_c=2^(cm-CC*nc),
// u_d*u_c = 2^(cm-CC) uniform. With m=(cm-CC)/2, s=2^m, w=2^(CC*nc-CC-m):
// direct = rcp(1+w*s), comp = w*rcp(w+s). One exp/pair instead of two.
__device__ __forceinline__ void pair_term(float nc, float negA, float s2m,
                                          float& sd, float& sc) {
    float w = exp2f_n(fmaf(nc, CC, negA));  // negA = -(CC + m)
    sd += rcpf(fmaf(w, s2m, 1.0f));
    sc += w * rcpf(w + s2m);
}
__device__ __forceinline__ float wave_max(float m) {
#pragma unroll
    for (int o = 32; o > 0; o >>= 1) m = fmaxf(m, __shfl_down(m, o, 64));
    return m;
}
__device__ __forceinline__ float wave_sum(float s) {
#pragma unroll
    for (int o = 32; o > 0; o >>= 1) s += __shfl_down(s, o, 64);
    return s;
}

// packed 4x f16 pixel record (planes interleaved)
union H4 {
    uint64_t u;
    __half2 h2[2];
    __half h[4];
};

// ---------------- row-sweep mask conv sums (unchanged) -----------------------
struct NC {
    float n3[8], n4[8], n5[8], n6[7];
    float v;  // center value w[3][3]
};

template <int STRIDE>
__device__ __forceinline__ NC sweep(const float* rp) {
    NC o;
    float r2s, r3s, r4s;
    float cen0, cen1, cen2, cen3, cen4, cen5, cen6, cen7, cen8;
    {   // win row 0 = K6 row 0
        float c0 = rp[0], c1 = rp[1], c2 = rp[2], c3 = rp[3], c4 = rp[4], c5 = rp[5];
        float c45 = c4 + c5, c01 = c0 + c1;
        float S6 = (c01 + (c2 + c3)) + c45;
        o.n6[0] = c45; o.n6[1] = c01; o.n6[2] = S6; o.n6[3] = S6;
        o.n6[4] = S6;  o.n6[5] = S6;  o.n6[6] = S6;
    }
    rp += STRIDE;
    {   // win row 1 = K6 r1, K5 r0, K4 r0
        float c0 = rp[0], c1 = rp[1], c2 = rp[2], c3 = rp[3], c4 = rp[4], c5 = rp[5];
        float c45 = c4 + c5, c12 = c1 + c2, c34 = c3 + c4;
        float S4 = c12 + c34, S5 = S4 + c5;
        float c15 = c1 + c5, c05 = c0 + c5, c14 = c1 + c4;
        o.n6[0] += c5;  o.n6[1] += c0;  o.n6[2] += c05; o.n6[3] += c05;
        o.n6[4] += c0;  o.n6[5] += c5;  o.n6[6] += c05;
        o.n5[0] = c45; o.n5[1] = c12; o.n5[2] = S5; o.n5[3] = S5;
        o.n5[4] = S5;  o.n5[5] = S5;  o.n5[6] = S5; o.n5[7] = c15;
        o.n4[0] = c34; o.n4[1] = c12; o.n4[2] = S4; o.n4[3] = S4;
        o.n4[4] = c14; o.n4[5] = S4;  o.n4[6] = S4; o.n4[7] = S4;
    }
    rp += STRIDE;
    {   // win row 2 = K6 r2, K5 r1, K4 r1, K3 r0
        float c0 = rp[0], c1 = rp[1], c2 = rp[2], c3 = rp[3], c4 = rp[4], c5 = rp[5];
        float c05 = c0 + c5, c15 = c1 + c5, c14 = c1 + c4;
        r2s = (c2 + c3) + c4;
        cen0 = c2; cen1 = c3; cen2 = c4;
        o.n6[0] += c5;  o.n6[1] += c0;  o.n6[2] += c0;  o.n6[3] += c5;
        o.n6[4] += c0;  o.n6[5] += c5;  o.n6[6] += c05;
        o.n5[0] += c5;  o.n5[1] += c1;  o.n5[2] += c15; o.n5[3] += c15;
        o.n5[4] += c1;  o.n5[5] += c5;  o.n5[6] += c15; o.n5[7] += c15;
        o.n4[0] += c4;  o.n4[1] += c1;  o.n4[2] += c14; o.n4[3] += c14;
        o.n4[4] += c14; o.n4[5] += c4;  o.n4[6] += c14; o.n4[7] += c1;
    }
    rp += STRIDE;
    {   // win row 3 = K6 r3, K5 r2, K4 r2, K3 r1 (center row)
        float c0 = rp[0], c1 = rp[1], c2 = rp[2], c3 = rp[3], c4 = rp[4], c5 = rp[5];
        float c05 = c0 + c5, c15 = c1 + c5, c14 = c1 + c4;
        r3s = (c2 + c3) + c4;
        cen3 = c2; cen4 = c3; cen5 = c4;
        o.v = c3;
        o.n6[0] += c5;  o.n6[1] += c0;  o.n6[2] += c0;  o.n6[3] += c5;
        o.n6[4] += c0;  o.n6[5] += c5;  o.n6[6] += c05;
        o.n5[0] += c5;  o.n5[1] += c1;  o.n5[2] += c1;  o.n5[3] += c5;
        o.n5[4] += c1;  o.n5[5] += c5;  o.n5[6] += c15; o.n5[7] += c15;
        o.n4[0] += c14; o.n4[1] += c14; o.n4[2] += c4;  o.n4[3] += c1;
        o.n4[4] += c14; o.n4[5] += c4;  o.n4[6] += c14; o.n4[7] += c1;
    }
    rp += STRIDE;
    {   // win row 4 = K6 r4, K5 r3, K4 r3, K3 r2
        float c0 = rp[0], c1 = rp[1], c2 = rp[2], c3 = rp[3], c4 = rp[4], c5 = rp[5];
        float c05 = c0 + c5, c15 = c1 + c5, c12 = c1 + c2, c34 = c3 + c4;
        float S4 = c12 + c34, c14 = c1 + c4;
        r4s = (c2 + c3) + c4;
        cen6 = c2; cen7 = c3; cen8 = c4;
        o.n6[0] += c05; o.n6[1] += c05; o.n6[2] += c0;  o.n6[3] += c5;
        o.n6[4] += c0;  o.n6[5] += c5;  o.n6[6] += c05;
        o.n5[0] += c15; o.n5[1] += c15; o.n5[2] += c1;  o.n5[3] += c5;
        o.n5[4] += c1;  o.n5[5] += c5;  o.n5[6] += c15; o.n5[7] += c15;
        o.n4[0] += S4;  o.n4[1] += S4;  o.n4[2] += c34; o.n4[3] += c12;
        o.n4[4] += S4;  o.n4[5] += S4;  o.n4[6] += c14; o.n4[7] += S4;
    }
    rp += STRIDE;
    {   // win row 5 = K6 r5, K5 r4
        float c0 = rp[0], c1 = rp[1], c2 = rp[2], c3 = rp[3], c4 = rp[4], c5 = rp[5];
        float c45 = c4 + c5, c12 = c1 + c2;
        float t = c3 + c45, S5 = c12 + t, S6 = S5 + c0;
        float c01 = c0 + c1, c05 = c0 + c5, c15 = c1 + c5;
        o.n6[0] += S6;  o.n6[1] += S6;  o.n6[2] += c01; o.n6[3] += c45;
        o.n6[4] += S6;  o.n6[5] += S6;  o.n6[6] += c05;
        o.n5[0] += S5;  o.n5[1] += S5;  o.n5[2] += c12; o.n5[3] += c45;
        o.n5[4] += S5;  o.n5[5] += S5;  o.n5[6] += c15; o.n5[7] += S5;
    }
    // K3: all 8 masks = S33 - center - one distinct cell
    float S33 = (r2s + r3s) + r4s;
    float T = S33 - cen4;
    o.n3[0] = T - cen3; o.n3[1] = T - cen7; o.n3[2] = T - cen5; o.n3[3] = T - cen1;
    o.n3[4] = T - cen0; o.n3[5] = T - cen6; o.n3[6] = T - cen8; o.n3[7] = T - cen2;
    return o;
}

// class index per mask into per-class constants; counts {7,9,10,11,13,16}
__constant__ __device__ const int CI4[8] = {1, 1, 1, 1, 2, 2, 2, 2};
__constant__ __device__ const int CI5[8] = {3, 3, 3, 3, 4, 4, 4, 4};
__constant__ __device__ const int CI6[7] = {4, 4, 4, 4, 5, 5, 5};

// PAIR=true: negA[6] = -(CC+m_c), s2m[6] = 2^m_c (shared-exp pairs).
// PAIR=false: plain endsig on direct only (edge blocks).
template <bool PAIR>
__device__ __forceinline__ void ssum_from_nc(const NC& a, const float* negA,
                                             const float* s2m, float& sD,
                                             float& sC) {
    float sd = 0.0f, sc = 0.0f;
#pragma unroll
    for (int k = 0; k < 8; k++) {
        if constexpr (PAIR) pair_term(a.n3[k], negA[0], s2m[0], sd, sc);
        else sd += endsig(a.n3[k]);
    }
#pragma unroll
    for (int k = 0; k < 8; k++) {
        if constexpr (PAIR) pair_term(a.n4[k], negA[CI4[k]], s2m[CI4[k]], sd, sc);
        else sd += endsig(a.n4[k]);
    }
#pragma unroll
    for (int k = 0; k < 8; k++) {
        if constexpr (PAIR) pair_term(a.n5[k], negA[CI5[k]], s2m[CI5[k]], sd, sc);
        else sd += endsig(a.n5[k]);
    }
#pragma unroll
    for (int k = 0; k < 7; k++) {
        if constexpr (PAIR) pair_term(a.n6[k], negA[CI6[k]], s2m[CI6[k]], sd, sc);
        else sd += endsig(a.n6[k]);
    }
    sD = sd;
    sC = sc;
}

// build per-class pair constants from M: cm = CC*(cnt*M-1), m = (cm-CC)/2
__device__ __forceinline__ void build_pair_consts(float M, float* negA,
                                                  float* s2m) {
    const float cntf[6] = {7.0f, 9.0f, 10.0f, 11.0f, 13.0f, 16.0f};
#pragma unroll
    for (int c = 0; c < 6; c++) {
        float cm = fmaf(cntf[c] * M, CC, -CC);
        float m = 0.5f * (cm - CC);
        negA[c] = -(CC + m);
        s2m[c] = exp2f_n(m);
    }
}

// ---------------- cp_quad: multi-level (R10 structure; (256,8) residency) ----
// z-slice -> (lvl = lvl_base + z>>3, b = z&7). lvl selects input pair + M
// slots; pixel records at cp + 4*(lvl-plane_lvl0)*NPIX halves. One merged
// dispatch = one residency tail. (256,8): request 8 waves/EU (VGPR<=64).
// R14: output = interleaved H4 records -> single 8B store per thread.
__global__ __launch_bounds__(256, 8) void cp_quad_kernel(
    const float* __restrict__ x0P, const float* __restrict__ x0G,
    const float* __restrict__ x1P, const float* __restrict__ x1G,
    const float* __restrict__ x2P, const float* __restrict__ x2G,
    const float* __restrict__ S, int lvl_base, int plane_lvl0,
    __half* __restrict__ cp) {
    __shared__ float win[2][21][48];
    const int lvl = lvl_base + (blockIdx.z >> 3);
    const int b = blockIdx.z & 7;
    const float* xP = (lvl == 0) ? x0P : (lvl == 1) ? x1P : x2P;
    const float* xG = (lvl == 0) ? x0G : (lvl == 1) ? x1G : x2G;
    const float MP = S[lvl], MG = S[3 + lvl];
    __half* cpb = cp + (size_t)(4 * (lvl - plane_lvl0)) * NPIX;

    const int oy0 = blockIdx.y * 16, ox0 = blockIdx.x * 16;
    const bool edge = (blockIdx.x == 0) | (blockIdx.x == (W / 16 - 1)) |
                      (blockIdx.y == 0) | (blockIdx.y == (H / 16 - 1));
    const int tid = threadIdx.y * 16 + threadIdx.x;
    const int ty = threadIdx.y, tx = threadIdx.x;
    const int o = b * HW + (oy0 + ty) * W + (ox0 + tx);

    if (!edge) {
        const float* pb = xP + b * HW + (oy0 - 3) * W + (ox0 - 3);
        const float* gb = xG + b * HW + (oy0 - 3) * W + (ox0 - 3);
        for (int i = tid; i < 21 * 21; i += 256) {
            int r = i / 21, c = i % 21;
            win[0][r][c] = pb[r * W + c];
            win[1][r][c] = gb[r * W + c];
        }
        __syncthreads();
        float negA[6], s2m[6], sPd, sPc, sGd, sGc;
        build_pair_consts(MP, negA, s2m);
        NC a = sweep<48>(&win[0][ty][tx]);
        ssum_from_nc<true>(a, negA, s2m, sPd, sPc);
        build_pair_consts(MG, negA, s2m);
        NC g = sweep<48>(&win[1][ty][tx]);
        ssum_from_nc<true>(g, negA, s2m, sGd, sGc);
        H4 v;
        v.h[0] = __float2half(sig_cp(a.v * sPd));
        v.h[1] = __float2half(sig_cp(g.v * sGd));
        v.h[2] = __float2half(sig_cp((MP - a.v) * sPc));
        v.h[3] = __float2half(sig_cp((MG - g.v) * sGc));
        *(uint64_t*)(cpb + (size_t)o * 4) = v.u;
    } else {
        const float* pb = xP + b * HW;
        const float* gb = xG + b * HW;
        // phase A: direct planes
        for (int i = tid; i < 21 * 21; i += 256) {
            int r = i / 21, c = i % 21;
            int pr = oy0 - 2 + r;  // padded coords (0..513 valid)
            int pc = ox0 - 2 + c;
            float vP, vG;
            if (pr < 0 || pr > H + 1 || pc < 0 || pc > W + 1) {
                vP = vG = 0.0f;  // conv zero-pad
            } else if (pr == 0 || pr == H + 1 || pc == 0 || pc == W + 1) {
                vP = vG = 1.0f;  // image 1-pad
            } else {
                vP = pb[(pr - 1) * W + (pc - 1)];
                vG = gb[(pr - 1) * W + (pc - 1)];
            }
            win[0][r][c] = vP; win[1][r][c] = vG;
        }
        __syncthreads();
        float sPd, sPc, sGd, sGc, junk, vPd, vGd;
        NC a = sweep<48>(&win[0][ty][tx]);
        ssum_from_nc<false>(a, nullptr, nullptr, sPd, junk);  vPd = a.v;
        NC g = sweep<48>(&win[1][ty][tx]);
        ssum_from_nc<false>(g, nullptr, nullptr, sGd, junk);  vGd = g.v;
        __half2* po = (__half2*)(cpb + (size_t)o * 4);
        po[0] = __halves2half2(__float2half(sig_cp(vPd * sPd)),
                               __float2half(sig_cp(vGd * sGd)));
        __syncthreads();  // all reads of direct planes done
        // phase B: complement planes
        for (int i = tid; i < 21 * 21; i += 256) {
            int r = i / 21, c = i % 21;
            int pr = oy0 - 2 + r;
            int pc = ox0 - 2 + c;
            float vP, vG;
            if (pr < 0 || pr > H + 1 || pc < 0 || pc > W + 1) {
                vP = vG = 0.0f;
            } else if (pr == 0 || pr == H + 1 || pc == 0 || pc == W + 1) {
                vP = vG = 1.0f;
            } else {
                vP = MP - pb[(pr - 1) * W + (pc - 1)];
                vG = MG - gb[(pr - 1) * W + (pc - 1)];
            }
            win[0][r][c] = vP; win[1][r][c] = vG;
        }
        __syncthreads();
        NC ac = sweep<48>(&win[0][ty][tx]);
        ssum_from_nc<false>(ac, nullptr, nullptr, sPc, junk);
        NC gc = sweep<48>(&win[1][ty][tx]);
        ssum_from_nc<false>(gc, nullptr, nullptr, sGc, junk);
        po[1] = __halves2half2(__float2half(sig_cp(ac.v * sPc)),
                               __float2half(sig_cp(gc.v * sGc)));
    }
}

// ---------------- dil_diff: 8 rows/thread, interleaved f16, multi-level ------
__device__ __forceinline__ float4 h4_add(float4 a, uint64_t u) {
    H4 v; v.u = u;
    float2 p0 = __half22float2(v.h2[0]);
    float2 p1 = __half22float2(v.h2[1]);
    a.x += p0.x; a.y += p0.y; a.z += p1.x; a.w += p1.y;
    return a;
}

__global__ __launch_bounds__(256) void dil_diff2_kernel(
    const __half* __restrict__ cp, float* __restrict__ partial) {
    const int plane_grp = blockIdx.x >> 10;  // NBD=1024 blocks per level
    const int r = blockIdx.x & (NBD - 1);
    const __half* cpb = cp + (size_t)(4 * plane_grp) * NPIX;
    const int T = r * 256 + threadIdx.x;
    const int x = T & (W - 1);
    const int g = T >> 9;
    const int y0 = (g & 63) << 3;  // 64 rowgroups of 8 rows
    const int b = g >> 6;
    const __half* pb = cpb + (size_t)b * HW * 4;

    float4 rs[10];
#pragma unroll
    for (int j = 0; j < 10; j++) {
        int yy = y0 - 1 + j;
        float4 acc = make_float4(0.0f, 0.0f, 0.0f, 0.0f);
        if (yy >= 0 && yy < H) {  // wave-uniform
            const __half* row = pb + (size_t)yy * (W * 4);
            // center always in-range; left/right guarded (divergent only at
            // the two boundary lanes of the image row)
            if (x > 0)
                acc = h4_add(acc, *(const uint64_t*)(row + (size_t)(x - 1) * 4));
            acc = h4_add(acc, *(const uint64_t*)(row + (size_t)x * 4));
            if (x < W - 1)
                acc = h4_add(acc, *(const uint64_t*)(row + (size_t)(x + 1) * 4));
        }
        rs[j] = acc;
    }

    float s = 0.0f;
#pragma unroll
    for (int i = 0; i < 8; i++) {
        float s0 = (rs[i].x + rs[i + 1].x) + rs[i + 2].x;
        float s1 = (rs[i].y + rs[i + 1].y) + rs[i + 2].y;
        float s2 = (rs[i].z + rs[i + 1].z) + rs[i + 2].z;
        float s3 = (rs[i].w + rs[i + 1].w) + rs[i + 2].w;
        float d1 = fminf(s0, 1.0f) - fminf(s1, 1.0f);
        float d2 = fminf(s2, 1.0f) - fminf(s3, 1.0f);
        s += fmaf(d1, d1, d2 * d2);
    }
    s = wave_sum(s);
    __shared__ float red[4];
    int tid = threadIdx.x;
    if ((tid & 63) == 0) red[tid >> 6] = s;
    __syncthreads();
    if (tid == 0) partial[blockIdx.x] = (red[0] + red[1]) + (red[2] + red[3]);
}

// ---------------- cross-conv 4px/thread helper -------------------------------
__device__ __forceinline__ void cross4(const float* __restrict__ xp, int idx,
                                       int y, int c, float4& ctr, float t[4]) {
    const float4* v = (const float4*)(xp + idx);
    ctr = v[0];
    float4 up = (y > 0) ? *(const float4*)(xp + idx - W)
                        : make_float4(0, 0, 0, 0);
    float4 dn = (y < H - 1) ? *(const float4*)(xp + idx + W)
                            : make_float4(0, 0, 0, 0);
    float lf = (c > 0) ? xp[idx - 1] : 0.0f;
    float rt = (c < W - 4) ? xp[idx + 4] : 0.0f;
    t[0] = (up.x + dn.x) + (lf + ctr.y);
    t[1] = (up.y + dn.y) + (ctr.x + ctr.z);
    t[2] = (up.z + dn.z) + (ctr.y + ctr.w);
    t[3] = (up.w + dn.w) + (ctr.z + rt);
}

// ---------------- erosion: cross-conv max pass -> float4 partial/block -------
__global__ __launch_bounds__(256) void cross_max_both_kernel(
    const float* __restrict__ xP, const float* __restrict__ xG,
    float4* __restrict__ partial) {
    float mtP = 0, mtG = 0, mrP = 0, mrG = 0;
    for (int T = blockIdx.x * 256 + threadIdx.x; T < NPIX / 4; T += NB1 * 256) {
        int idx = T * 4;
        int i = idx & (HW - 1);
        int y = i >> 9;
        int c = i & (W - 1);
        float4 ctr;
        float t[4];
        cross4(xP, idx, y, c, ctr, t);
        mtP = fmaxf(mtP, fmaxf(fmaxf(t[0], t[1]), fmaxf(t[2], t[3])));
        mrP = fmaxf(mrP, fmaxf(fmaxf(ctr.x, ctr.y), fmaxf(ctr.z, ctr.w)));
        cross4(xG, idx, y, c, ctr, t);
        mtG = fmaxf(mtG, fmaxf(fmaxf(t[0], t[1]), fmaxf(t[2], t[3])));
        mrG = fmaxf(mrG, fmaxf(fmaxf(ctr.x, ctr.y), fmaxf(ctr.z, ctr.w)));
    }
    mtP = wave_max(mtP); mtG = wave_max(mtG);
    mrP = wave_max(mrP); mrG = wave_max(mrG);
    __shared__ float red[4][4];
    int tid = threadIdx.x;
    if ((tid & 63) == 0) {
        int w = tid >> 6;
        red[w][0] = mtP; red[w][1] = mtG; red[w][2] = mrP; red[w][3] = mrG;
    }
    __syncthreads();
    if (tid == 0) {
        float4 r;
        r.x = fmaxf(fmaxf(red[0][0], red[1][0]), fmaxf(red[2][0], red[3][0]));
        r.y = fmaxf(fmaxf(red[0][1], red[1][1]), fmaxf(red[2][1], red[3][1]));
        r.z = fmaxf(fmaxf(red[0][2], red[1][2]), fmaxf(red[2][2], red[3][2]));
        r.w = fmaxf(fmaxf(red[0][3], red[1][3]), fmaxf(red[2][3], red[3][3]));
        partial[blockIdx.x] = r;
    }
}

// ---------------- erosion: fused PM-reduce + cross conv + normalize ----------
__global__ __launch_bounds__(256) void erode_both_kernel(
    const float* __restrict__ xP, const float* __restrict__ xG,
    const float4* __restrict__ PM,
    float* __restrict__ yP, float* __restrict__ yG,
    float* ymaxP, float* ymaxG, float* rmaxP, float* rmaxG) {
    // redundant per-block PM reduce (16KB, L2-resident)
    float a = 0, bm = 0, c4 = 0, d4 = 0;
    {
        int t = threadIdx.x;
#pragma unroll
        for (int k = 0; k < NB1 / 256; k++) {
            float4 p = PM[t + k * 256];
            a = fmaxf(a, p.x); bm = fmaxf(bm, p.y);
            c4 = fmaxf(c4, p.z); d4 = fmaxf(d4, p.w);
        }
        a = wave_max(a); bm = wave_max(bm); c4 = wave_max(c4); d4 = wave_max(d4);
        __shared__ float red[4][4];
        if ((t & 63) == 0) {
            int w = t >> 6;
            red[w][0] = a; red[w][1] = bm; red[w][2] = c4; red[w][3] = d4;
        }
        __syncthreads();
        a  = fmaxf(fmaxf(red[0][0], red[1][0]), fmaxf(red[2][0], red[3][0]));
        bm = fmaxf(fmaxf(red[0][1], red[1][1]), fmaxf(red[2][1], red[3][1]));
        c4 = fmaxf(fmaxf(red[0][2], red[1][2]), fmaxf(red[2][2], red[3][2]));
        d4 = fmaxf(fmaxf(red[0][3], red[1][3]), fmaxf(red[2][3], red[3][3]));
    }
    const float tP_max = a, tG_max = bm;
    const float invP = rcpf(tP_max + 1e-8f);
    const float invG = rcpf(tG_max + 1e-8f);

    const int T = blockIdx.x * 256 + threadIdx.x;  // 2048 blocks cover NPIX/4
    if (T < NPIX / 4) {
        int idx = T * 4;
        int i = idx & (HW - 1);
        int y = i >> 9;
        int c = i & (W - 1);
        float4 ctr;
        float t[4], o[4];
        cross4(xP, idx, y, c, ctr, t);
#pragma unroll
        for (int k = 0; k < 4; k++) o[k] = sig_er(t[k] * invP);
        *(float4*)(yP + idx) = make_float4(o[0], o[1], o[2], o[3]);
        cross4(xG, idx, y, c, ctr, t);
#pragma unroll
        for (int k = 0; k < 4; k++) o[k] = sig_er(t[k] * invG);
        *(float4*)(yG + idx) = make_float4(o[0], o[1], o[2], o[3]);
    }
    if (blockIdx.x == 0 && threadIdx.x == 0) {
        *ymaxP = sig_er(tP_max * invP);
        *ymaxG = sig_er(tG_max * invG);
        *rmaxP = c4;
        *rmaxG = d4;
    }
}

// ---------------- final: sum 3*NBD partials, /B ------------------------------
__global__ __launch_bounds__(1024) void finalize_kernel(
    const float* __restrict__ PS, float* out) {
    int t = threadIdx.x;
    float s = PS[t] + PS[t + NBD] + PS[t + 2 * NBD];
    s = wave_sum(s);
    __shared__ float red[16];
    if ((t & 63) == 0) red[t >> 6] = s;
    __syncthreads();
    if (t == 0) {
        float tot = 0.0f;
#pragma unroll
        for (int i = 0; i < 16; i++) tot += red[i];
        out[0] = tot * (1.0f / (float)B);
    }
}

// ---------------- launch -----------------------------------------------------
extern "C" void kernel_launch(void* const* d_in, const int* in_sizes, int n_in,
                              void* d_out, int out_size, void* d_ws, size_t ws_size,
                              hipStream_t stream) {
    (void)in_sizes; (void)n_in; (void)out_size;
    const float* pred = (const float*)d_in[0];
    const float* gt   = (const float*)d_in[1];
    float* out = (float*)d_out;

    // ws (floats): S[64] | PM[4*NB1] | PS[3*NBD] | P1,G1,P2,G2 | CP (f16)
    float* S  = (float*)d_ws;
    float4* PM = (float4*)(S + 64);
    float* PS = S + 64 + 4 * NB1;
    float* P1 = PS + 3 * NBD;
    float* G1 = P1 + NPIX;
    float* P2 = G1 + NPIX;
    float* G2 = P2 + NPIX;
    __half* CP = (__half*)(G2 + NPIX);

    // merged path needs 12 f16 CP planes (48MB); fallback (R9 schedule) needs 4
    const size_t base_b = (size_t)(64 + 4 * NB1 + 3 * NBD) * 4 +
                          (size_t)4 * NPIX * 4;
    const bool merged = ws_size >= base_b + (size_t)12 * NPIX * 2;

    const dim3 b1(256), g1(NB1), gE(NPIX / 4 / 256);
    const dim3 b2(16, 16, 1);

    // erosion chain
    cross_max_both_kernel<<<g1, b1, 0, stream>>>(pred, gt, PM);
    erode_both_kernel<<<gE, b1, 0, stream>>>(pred, gt, PM, P1, G1,
                                             S + 1, S + 4, S + 0, S + 3);
    cross_max_both_kernel<<<g1, b1, 0, stream>>>(P1, G1, PM);
    erode_both_kernel<<<gE, b1, 0, stream>>>(P1, G1, PM, P2, G2,
                                             S + 2, S + 5, S + 12, S + 13);

    if (merged) {
        // all 3 levels in one cp dispatch (one tail) + one dil dispatch
        cp_quad_kernel<<<dim3(W / 16, H / 16, 3 * B), b2, 0, stream>>>(
            pred, gt, P1, G1, P2, G2, S, 0, 0, CP);
        dil_diff2_kernel<<<dim3(3 * NBD), b1, 0, stream>>>(CP, PS);
    } else {
        for (int lvl = 0; lvl < 3; lvl++) {
            cp_quad_kernel<<<dim3(W / 16, H / 16, B), b2, 0, stream>>>(
                pred, gt, P1, G1, P2, G2, S, lvl, lvl, CP);
            dil_diff2_kernel<<<dim3(NBD), b1, 0, stream>>>(CP, PS + lvl * NBD);
        }
    }

    finalize_kernel<<<1, 1024, 0, stream>>>(PS, out);
}

// Round 2
// 314.760 us; speedup vs baseline: 1.1212x; 1.1212x over previous
//
#include <hip/hip_runtime.h>
#include <hip/hip_fp16.h>
#include <cstdint>

// Problem constants (setup_inputs: B=8, H=W=512, num_erosions=2)
static constexpr int B = 8;
static constexpr int H = 512;
static constexpr int W = 512;
static constexpr int HW = H * W;
static constexpr int NPIX = B * HW;
static constexpr int NB1 = 1024;  // blocks for cross_max partials
static constexpr int NBD = 1024;  // blocks per dil_diff level

// 10*log2(e): sigmoid(10*z) = 1/(1+2^(-CC*z))
static constexpr float CC = 14.4269504088896f;

// ---------------- helpers ----------------------------------------------------
// R14: CP planes interleaved per pixel (8B records) -> WRITE_SIZE 419->117MB,
//   FETCH 215->101MB, but dur unchanged => cp_quad is VALU-issue-bound, not
//   memory-bound (VALUBusy 78%, HBM 11%).
// R15: pack P,G into f32x2 lanes (VOP3P v_pk_fma_f32/v_pk_add_f32). ONE f2
//   sweep replaces two scalar sweeps (halves sweep adds + LDS reads, b64);
//   ssum fast ops pack 2-wide. Transcendentals (exp/rcp) stay scalar per
//   component — unchanged count. launch_bounds (256,4): cap VGPR at 128
//   (f2 NC state ~64 regs), no spills; 8 waves/SIMD still allowed if <=64.
__device__ __forceinline__ float rcpf(float x) { return __builtin_amdgcn_rcpf(x); }
__device__ __forceinline__ float exp2f_n(float x) { return __builtin_amdgcn_exp2f(x); }

typedef __attribute__((ext_vector_type(2))) float f2;

__device__ __forceinline__ f2 mk2(float a, float b) { f2 r; r.x = a; r.y = b; return r; }
__device__ __forceinline__ f2 exp2_2(f2 v) {
    f2 r; r.x = exp2f_n(v.x); r.y = exp2f_n(v.y); return r;
}
__device__ __forceinline__ f2 rcp_2(f2 v) {
    f2 r; r.x = rcpf(v.x); r.y = rcpf(v.y); return r;
}
#if defined(__has_builtin)
#if __has_builtin(__builtin_elementwise_fma)
#define FMA2(a, b, c) __builtin_elementwise_fma((a), (b), (c))
#endif
#endif
#ifndef FMA2
__device__ __forceinline__ f2 fma2_(f2 a, f2 b, f2 c) {
    f2 r; r.x = fmaf(a.x, b.x, c.x); r.y = fmaf(a.y, b.y, c.y); return r;
}
#define FMA2(a, b, c) fma2_((a), (b), (c))
#endif

__device__ __forceinline__ float endsig(float nc) {
    return rcpf(1.0f + exp2f_n(fmaf(nc, CC, -CC)));
}
__device__ __forceinline__ float sig_cp(float x) {  // sigmoid(10(x-0.5))
    return rcpf(1.0f + exp2f_n(fmaf(x, -CC, 0.5f * CC)));
}
__device__ __forceinline__ float sig_er(float r) {  // sigmoid(10(r-0.7))
    return rcpf(1.0f + exp2f_n(fmaf(r, -CC, 0.7f * CC)));
}
// Shared-exp complement pair (R12): one exp per (direct, complement) pair.
// f2 lanes carry (P, G). negA = -(CC+m), s2m = 2^m per class per image.
__device__ __forceinline__ void pair_term2(f2 nc, f2 negA, f2 s2m,
                                           f2& sd, f2& sc) {
    const f2 CC2 = CC;
    const f2 one2 = 1.0f;
    f2 w = exp2_2(FMA2(nc, CC2, negA));
    sd += rcp_2(FMA2(w, s2m, one2));
    sc += w * rcp_2(w + s2m);
}
// plain direct-only sigmoid (edge blocks), f2 lanes (P, G)
__device__ __forceinline__ void end_term2(f2 nc, f2& sd) {
    const f2 CC2 = CC;
    const f2 nCC2 = -CC;
    const f2 one2 = 1.0f;
    sd += rcp_2(one2 + exp2_2(FMA2(nc, CC2, nCC2)));
}
__device__ __forceinline__ float wave_max(float m) {
#pragma unroll
    for (int o = 32; o > 0; o >>= 1) m = fmaxf(m, __shfl_down(m, o, 64));
    return m;
}
__device__ __forceinline__ float wave_sum(float s) {
#pragma unroll
    for (int o = 32; o > 0; o >>= 1) s += __shfl_down(s, o, 64);
    return s;
}

// packed 4x f16 pixel record (planes interleaved)
union H4 {
    uint64_t u;
    __half2 h2[2];
    __half h[4];
};

// ---------------- row-sweep mask conv sums (f2: lanes = P,G) -----------------
struct NC2 {
    f2 n3[8], n4[8], n5[8], n6[7];
    f2 v;  // center value w[3][3]
};

template <int STRIDE>
__device__ __forceinline__ NC2 sweep2(const f2* rp) {
    NC2 o;
    f2 r2s, r3s, r4s;
    f2 cen0, cen1, cen2, cen3, cen4, cen5, cen6, cen7, cen8;
    {   // win row 0 = K6 row 0
        f2 c0 = rp[0], c1 = rp[1], c2 = rp[2], c3 = rp[3], c4 = rp[4], c5 = rp[5];
        f2 c45 = c4 + c5, c01 = c0 + c1;
        f2 S6 = (c01 + (c2 + c3)) + c45;
        o.n6[0] = c45; o.n6[1] = c01; o.n6[2] = S6; o.n6[3] = S6;
        o.n6[4] = S6;  o.n6[5] = S6;  o.n6[6] = S6;
    }
    rp += STRIDE;
    {   // win row 1 = K6 r1, K5 r0, K4 r0
        f2 c0 = rp[0], c1 = rp[1], c2 = rp[2], c3 = rp[3], c4 = rp[4], c5 = rp[5];
        f2 c45 = c4 + c5, c12 = c1 + c2, c34 = c3 + c4;
        f2 S4 = c12 + c34, S5 = S4 + c5;
        f2 c15 = c1 + c5, c05 = c0 + c5, c14 = c1 + c4;
        o.n6[0] += c5;  o.n6[1] += c0;  o.n6[2] += c05; o.n6[3] += c05;
        o.n6[4] += c0;  o.n6[5] += c5;  o.n6[6] += c05;
        o.n5[0] = c45; o.n5[1] = c12; o.n5[2] = S5; o.n5[3] = S5;
        o.n5[4] = S5;  o.n5[5] = S5;  o.n5[6] = S5; o.n5[7] = c15;
        o.n4[0] = c34; o.n4[1] = c12; o.n4[2] = S4; o.n4[3] = S4;
        o.n4[4] = c14; o.n4[5] = S4;  o.n4[6] = S4; o.n4[7] = S4;
    }
    rp += STRIDE;
    {   // win row 2 = K6 r2, K5 r1, K4 r1, K3 r0
        f2 c0 = rp[0], c1 = rp[1], c2 = rp[2], c3 = rp[3], c4 = rp[4], c5 = rp[5];
        f2 c05 = c0 + c5, c15 = c1 + c5, c14 = c1 + c4;
        r2s = (c2 + c3) + c4;
        cen0 = c2; cen1 = c3; cen2 = c4;
        o.n6[0] += c5;  o.n6[1] += c0;  o.n6[2] += c0;  o.n6[3] += c5;
        o.n6[4] += c0;  o.n6[5] += c5;  o.n6[6] += c05;
        o.n5[0] += c5;  o.n5[1] += c1;  o.n5[2] += c15; o.n5[3] += c15;
        o.n5[4] += c1;  o.n5[5] += c5;  o.n5[6] += c15; o.n5[7] += c15;
        o.n4[0] += c4;  o.n4[1] += c1;  o.n4[2] += c14; o.n4[3] += c14;
        o.n4[4] += c14; o.n4[5] += c4;  o.n4[6] += c14; o.n4[7] += c1;
    }
    rp += STRIDE;
    {   // win row 3 = K6 r3, K5 r2, K4 r2, K3 r1 (center row)
        f2 c0 = rp[0], c1 = rp[1], c2 = rp[2], c3 = rp[3], c4 = rp[4], c5 = rp[5];
        f2 c05 = c0 + c5, c15 = c1 + c5, c14 = c1 + c4;
        r3s = (c2 + c3) + c4;
        cen3 = c2; cen4 = c3; cen5 = c4;
        o.v = c3;
        o.n6[0] += c5;  o.n6[1] += c0;  o.n6[2] += c0;  o.n6[3] += c5;
        o.n6[4] += c0;  o.n6[5] += c5;  o.n6[6] += c05;
        o.n5[0] += c5;  o.n5[1] += c1;  o.n5[2] += c1;  o.n5[3] += c5;
        o.n5[4] += c1;  o.n5[5] += c5;  o.n5[6] += c15; o.n5[7] += c15;
        o.n4[0] += c14; o.n4[1] += c14; o.n4[2] += c4;  o.n4[3] += c1;
        o.n4[4] += c14; o.n4[5] += c4;  o.n4[6] += c14; o.n4[7] += c1;
    }
    rp += STRIDE;
    {   // win row 4 = K6 r4, K5 r3, K4 r3, K3 r2
        f2 c0 = rp[0], c1 = rp[1], c2 = rp[2], c3 = rp[3], c4 = rp[4], c5 = rp[5];
        f2 c05 = c0 + c5, c15 = c1 + c5, c12 = c1 + c2, c34 = c3 + c4;
        f2 S4 = c12 + c34, c14 = c1 + c4;
        r4s = (c2 + c3) + c4;
        cen6 = c2; cen7 = c3; cen8 = c4;
        o.n6[0] += c05; o.n6[1] += c05; o.n6[2] += c0;  o.n6[3] += c5;
        o.n6[4] += c0;  o.n6[5] += c5;  o.n6[6] += c05;
        o.n5[0] += c15; o.n5[1] += c15; o.n5[2] += c1;  o.n5[3] += c5;
        o.n5[4] += c1;  o.n5[5] += c5;  o.n5[6] += c15; o.n5[7] += c15;
        o.n4[0] += S4;  o.n4[1] += S4;  o.n4[2] += c34; o.n4[3] += c12;
        o.n4[4] += S4;  o.n4[5] += S4;  o.n4[6] += c14; o.n4[7] += S4;
    }
    rp += STRIDE;
    {   // win row 5 = K6 r5, K5 r4
        f2 c0 = rp[0], c1 = rp[1], c2 = rp[2], c3 = rp[3], c4 = rp[4], c5 = rp[5];
        f2 c45 = c4 + c5, c12 = c1 + c2;
        f2 t = c3 + c45, S5 = c12 + t, S6 = S5 + c0;
        f2 c01 = c0 + c1, c05 = c0 + c5, c15 = c1 + c5;
        o.n6[0] += S6;  o.n6[1] += S6;  o.n6[2] += c01; o.n6[3] += c45;
        o.n6[4] += S6;  o.n6[5] += S6;  o.n6[6] += c05;
        o.n5[0] += S5;  o.n5[1] += S5;  o.n5[2] += c12; o.n5[3] += c45;
        o.n5[4] += S5;  o.n5[5] += S5;  o.n5[6] += c15; o.n5[7] += S5;
    }
    // K3: all 8 masks = S33 - center - one distinct cell
    f2 S33 = (r2s + r3s) + r4s;
    f2 T = S33 - cen4;
    o.n3[0] = T - cen3; o.n3[1] = T - cen7; o.n3[2] = T - cen5; o.n3[3] = T - cen1;
    o.n3[4] = T - cen0; o.n3[5] = T - cen6; o.n3[6] = T - cen8; o.n3[7] = T - cen2;
    return o;
}

// class index per mask into per-class constants; counts {7,9,10,11,13,16}
__constant__ __device__ const int CI4[8] = {1, 1, 1, 1, 2, 2, 2, 2};
__constant__ __device__ const int CI5[8] = {3, 3, 3, 3, 4, 4, 4, 4};
__constant__ __device__ const int CI6[7] = {4, 4, 4, 4, 5, 5, 5};

// PAIR=true: negA[6] = -(CC+m_c), s2m[6] = 2^m_c (shared-exp pairs).
// PAIR=false: plain endsig on direct only (edge blocks).
template <bool PAIR>
__device__ __forceinline__ void ssum_from_nc2(const NC2& a, const f2* negA,
                                              const f2* s2m, f2& sD, f2& sC) {
    f2 sd = 0.0f, sc = 0.0f;
#pragma unroll
    for (int k = 0; k < 8; k++) {
        if constexpr (PAIR) pair_term2(a.n3[k], negA[0], s2m[0], sd, sc);
        else end_term2(a.n3[k], sd);
    }
#pragma unroll
    for (int k = 0; k < 8; k++) {
        if constexpr (PAIR) pair_term2(a.n4[k], negA[CI4[k]], s2m[CI4[k]], sd, sc);
        else end_term2(a.n4[k], sd);
    }
#pragma unroll
    for (int k = 0; k < 8; k++) {
        if constexpr (PAIR) pair_term2(a.n5[k], negA[CI5[k]], s2m[CI5[k]], sd, sc);
        else end_term2(a.n5[k], sd);
    }
#pragma unroll
    for (int k = 0; k < 7; k++) {
        if constexpr (PAIR) pair_term2(a.n6[k], negA[CI6[k]], s2m[CI6[k]], sd, sc);
        else end_term2(a.n6[k], sd);
    }
    sD = sd;
    sC = sc;
}

// build per-class pair constants from (MP,MG): cm = CC*(cnt*M-1), m=(cm-CC)/2
__device__ __forceinline__ void build_pair_consts2(float MP, float MG,
                                                   f2* negA, f2* s2m) {
    const float cntf[6] = {7.0f, 9.0f, 10.0f, 11.0f, 13.0f, 16.0f};
#pragma unroll
    for (int c = 0; c < 6; c++) {
        float cmP = fmaf(cntf[c] * MP, CC, -CC);
        float mP = 0.5f * (cmP - CC);
        float cmG = fmaf(cntf[c] * MG, CC, -CC);
        float mG = 0.5f * (cmG - CC);
        negA[c] = mk2(-(CC + mP), -(CC + mG));
        s2m[c] = mk2(exp2f_n(mP), exp2f_n(mG));
    }
}

// ---------------- cp_quad: multi-level, f2-packed (P,G) ----------------------
// z-slice -> (lvl = lvl_base + z>>3, b = z&7). One f2 sweep covers both
// images; ssum packs fast ops 2-wide. Output = interleaved H4 record (8B).
// LDS win[21][49] f2: row stride 49*8B -> b64 reads land at the 4-words/bank
// floor (no extra conflicts).
__global__ __launch_bounds__(256, 4) void cp_quad_kernel(
    const float* __restrict__ x0P, const float* __restrict__ x0G,
    const float* __restrict__ x1P, const float* __restrict__ x1G,
    const float* __restrict__ x2P, const float* __restrict__ x2G,
    const float* __restrict__ S, int lvl_base, int plane_lvl0,
    __half* __restrict__ cp) {
    __shared__ f2 win[21][49];
    const int lvl = lvl_base + (blockIdx.z >> 3);
    const int b = blockIdx.z & 7;
    const float* xP = (lvl == 0) ? x0P : (lvl == 1) ? x1P : x2P;
    const float* xG = (lvl == 0) ? x0G : (lvl == 1) ? x1G : x2G;
    const float MP = S[lvl], MG = S[3 + lvl];
    __half* cpb = cp + (size_t)(4 * (lvl - plane_lvl0)) * NPIX;

    const int oy0 = blockIdx.y * 16, ox0 = blockIdx.x * 16;
    const bool edge = (blockIdx.x == 0) | (blockIdx.x == (W / 16 - 1)) |
                      (blockIdx.y == 0) | (blockIdx.y == (H / 16 - 1));
    const int tid = threadIdx.y * 16 + threadIdx.x;
    const int ty = threadIdx.y, tx = threadIdx.x;
    const int o = b * HW + (oy0 + ty) * W + (ox0 + tx);

    if (!edge) {
        const float* pb = xP + b * HW + (oy0 - 3) * W + (ox0 - 3);
        const float* gb = xG + b * HW + (oy0 - 3) * W + (ox0 - 3);
        for (int i = tid; i < 21 * 21; i += 256) {
            int r = i / 21, c = i % 21;
            win[r][c] = mk2(pb[r * W + c], gb[r * W + c]);
        }
        __syncthreads();
        f2 negA[6], s2m[6], sd, sc;
        build_pair_consts2(MP, MG, negA, s2m);
        NC2 a = sweep2<49>(&win[ty][tx]);
        ssum_from_nc2<true>(a, negA, s2m, sd, sc);
        H4 v;
        v.h[0] = __float2half(sig_cp(a.v.x * sd.x));
        v.h[1] = __float2half(sig_cp(a.v.y * sd.y));
        v.h[2] = __float2half(sig_cp((MP - a.v.x) * sc.x));
        v.h[3] = __float2half(sig_cp((MG - a.v.y) * sc.y));
        *(uint64_t*)(cpb + (size_t)o * 4) = v.u;
    } else {
        const float* pb = xP + b * HW;
        const float* gb = xG + b * HW;
        // phase A: direct planes
        for (int i = tid; i < 21 * 21; i += 256) {
            int r = i / 21, c = i % 21;
            int pr = oy0 - 2 + r;  // padded coords (0..513 valid)
            int pc = ox0 - 2 + c;
            f2 v;
            if (pr < 0 || pr > H + 1 || pc < 0 || pc > W + 1) {
                v = 0.0f;  // conv zero-pad
            } else if (pr == 0 || pr == H + 1 || pc == 0 || pc == W + 1) {
                v = 1.0f;  // image 1-pad
            } else {
                v = mk2(pb[(pr - 1) * W + (pc - 1)], gb[(pr - 1) * W + (pc - 1)]);
            }
            win[r][c] = v;
        }
        __syncthreads();
        f2 sd, sc, junk;
        NC2 a = sweep2<49>(&win[ty][tx]);
        ssum_from_nc2<false>(a, nullptr, nullptr, sd, junk);
        f2 vD = a.v;
        __half2* po = (__half2*)(cpb + (size_t)o * 4);
        po[0] = __halves2half2(__float2half(sig_cp(vD.x * sd.x)),
                               __float2half(sig_cp(vD.y * sd.y)));
        __syncthreads();  // all reads of direct planes done
        // phase B: complement planes
        for (int i = tid; i < 21 * 21; i += 256) {
            int r = i / 21, c = i % 21;
            int pr = oy0 - 2 + r;
            int pc = ox0 - 2 + c;
            f2 v;
            if (pr < 0 || pr > H + 1 || pc < 0 || pc > W + 1) {
                v = 0.0f;
            } else if (pr == 0 || pr == H + 1 || pc == 0 || pc == W + 1) {
                v = 1.0f;
            } else {
                v = mk2(MP - pb[(pr - 1) * W + (pc - 1)],
                        MG - gb[(pr - 1) * W + (pc - 1)]);
            }
            win[r][c] = v;
        }
        __syncthreads();
        NC2 ac = sweep2<49>(&win[ty][tx]);
        ssum_from_nc2<false>(ac, nullptr, nullptr, sc, junk);
        po[1] = __halves2half2(__float2half(sig_cp(ac.v.x * sc.x)),
                               __float2half(sig_cp(ac.v.y * sc.y)));
    }
}

// ---------------- dil_diff: 8 rows/thread, interleaved f16, multi-level ------
__device__ __forceinline__ float4 h4_add(float4 a, uint64_t u) {
    H4 v; v.u = u;
    float2 p0 = __half22float2(v.h2[0]);
    float2 p1 = __half22float2(v.h2[1]);
    a.x += p0.x; a.y += p0.y; a.z += p1.x; a.w += p1.y;
    return a;
}

__global__ __launch_bounds__(256) void dil_diff2_kernel(
    const __half* __restrict__ cp, float* __restrict__ partial) {
    const int plane_grp = blockIdx.x >> 10;  // NBD=1024 blocks per level
    const int r = blockIdx.x & (NBD - 1);
    const __half* cpb = cp + (size_t)(4 * plane_grp) * NPIX;
    const int T = r * 256 + threadIdx.x;
    const int x = T & (W - 1);
    const int g = T >> 9;
    const int y0 = (g & 63) << 3;  // 64 rowgroups of 8 rows
    const int b = g >> 6;
    const __half* pb = cpb + (size_t)b * HW * 4;

    float4 rs[10];
#pragma unroll
    for (int j = 0; j < 10; j++) {
        int yy = y0 - 1 + j;
        float4 acc = make_float4(0.0f, 0.0f, 0.0f, 0.0f);
        if (yy >= 0 && yy < H) {  // wave-uniform
            const __half* row = pb + (size_t)yy * (W * 4);
            if (x > 0)
                acc = h4_add(acc, *(const uint64_t*)(row + (size_t)(x - 1) * 4));
            acc = h4_add(acc, *(const uint64_t*)(row + (size_t)x * 4));
            if (x < W - 1)
                acc = h4_add(acc, *(const uint64_t*)(row + (size_t)(x + 1) * 4));
        }
        rs[j] = acc;
    }

    float s = 0.0f;
#pragma unroll
    for (int i = 0; i < 8; i++) {
        float s0 = (rs[i].x + rs[i + 1].x) + rs[i + 2].x;
        float s1 = (rs[i].y + rs[i + 1].y) + rs[i + 2].y;
        float s2 = (rs[i].z + rs[i + 1].z) + rs[i + 2].z;
        float s3 = (rs[i].w + rs[i + 1].w) + rs[i + 2].w;
        float d1 = fminf(s0, 1.0f) - fminf(s1, 1.0f);
        float d2 = fminf(s2, 1.0f) - fminf(s3, 1.0f);
        s += fmaf(d1, d1, d2 * d2);
    }
    s = wave_sum(s);
    __shared__ float red[4];
    int tid = threadIdx.x;
    if ((tid & 63) == 0) red[tid >> 6] = s;
    __syncthreads();
    if (tid == 0) partial[blockIdx.x] = (red[0] + red[1]) + (red[2] + red[3]);
}

// ---------------- cross-conv 4px/thread helper -------------------------------
__device__ __forceinline__ void cross4(const float* __restrict__ xp, int idx,
                                       int y, int c, float4& ctr, float t[4]) {
    const float4* v = (const float4*)(xp + idx);
    ctr = v[0];
    float4 up = (y > 0) ? *(const float4*)(xp + idx - W)
                        : make_float4(0, 0, 0, 0);
    float4 dn = (y < H - 1) ? *(const float4*)(xp + idx + W)
                            : make_float4(0, 0, 0, 0);
    float lf = (c > 0) ? xp[idx - 1] : 0.0f;
    float rt = (c < W - 4) ? xp[idx + 4] : 0.0f;
    t[0] = (up.x + dn.x) + (lf + ctr.y);
    t[1] = (up.y + dn.y) + (ctr.x + ctr.z);
    t[2] = (up.z + dn.z) + (ctr.y + ctr.w);
    t[3] = (up.w + dn.w) + (ctr.z + rt);
}

// ---------------- erosion: cross-conv max pass -> float4 partial/block -------
__global__ __launch_bounds__(256) void cross_max_both_kernel(
    const float* __restrict__ xP, const float* __restrict__ xG,
    float4* __restrict__ partial) {
    float mtP = 0, mtG = 0, mrP = 0, mrG = 0;
    for (int T = blockIdx.x * 256 + threadIdx.x; T < NPIX / 4; T += NB1 * 256) {
        int idx = T * 4;
        int i = idx & (HW - 1);
        int y = i >> 9;
        int c = i & (W - 1);
        float4 ctr;
        float t[4];
        cross4(xP, idx, y, c, ctr, t);
        mtP = fmaxf(mtP, fmaxf(fmaxf(t[0], t[1]), fmaxf(t[2], t[3])));
        mrP = fmaxf(mrP, fmaxf(fmaxf(ctr.x, ctr.y), fmaxf(ctr.z, ctr.w)));
        cross4(xG, idx, y, c, ctr, t);
        mtG = fmaxf(mtG, fmaxf(fmaxf(t[0], t[1]), fmaxf(t[2], t[3])));
        mrG = fmaxf(mrG, fmaxf(fmaxf(ctr.x, ctr.y), fmaxf(ctr.z, ctr.w)));
    }
    mtP = wave_max(mtP); mtG = wave_max(mtG);
    mrP = wave_max(mrP); mrG = wave_max(mrG);
    __shared__ float red[4][4];
    int tid = threadIdx.x;
    if ((tid & 63) == 0) {
        int w = tid >> 6;
        red[w][0] = mtP; red[w][1] = mtG; red[w][2] = mrP; red[w][3] = mrG;
    }
    __syncthreads();
    if (tid == 0) {
        float4 r;
        r.x = fmaxf(fmaxf(red[0][0], red[1][0]), fmaxf(red[2][0], red[3][0]));
        r.y = fmaxf(fmaxf(red[0][1], red[1][1]), fmaxf(red[2][1], red[3][1]));
        r.z = fmaxf(fmaxf(red[0][2], red[1][2]), fmaxf(red[2][2], red[3][2]));
        r.w = fmaxf(fmaxf(red[0][3], red[1][3]), fmaxf(red[2][3], red[3][3]));
        partial[blockIdx.x] = r;
    }
}

// ---------------- erosion: fused PM-reduce + cross conv + normalize ----------
__global__ __launch_bounds__(256) void erode_both_kernel(
    const float* __restrict__ xP, const float* __restrict__ xG,
    const float4* __restrict__ PM,
    float* __restrict__ yP, float* __restrict__ yG,
    float* ymaxP, float* ymaxG, float* rmaxP, float* rmaxG) {
    // redundant per-block PM reduce (16KB, L2-resident)
    float a = 0, bm = 0, c4 = 0, d4 = 0;
    {
        int t = threadIdx.x;
#pragma unroll
        for (int k = 0; k < NB1 / 256; k++) {
            float4 p = PM[t + k * 256];
            a = fmaxf(a, p.x); bm = fmaxf(bm, p.y);
            c4 = fmaxf(c4, p.z); d4 = fmaxf(d4, p.w);
        }
        a = wave_max(a); bm = wave_max(bm); c4 = wave_max(c4); d4 = wave_max(d4);
        __shared__ float red[4][4];
        if ((t & 63) == 0) {
            int w = t >> 6;
            red[w][0] = a; red[w][1] = bm; red[w][2] = c4; red[w][3] = d4;
        }
        __syncthreads();
        a  = fmaxf(fmaxf(red[0][0], red[1][0]), fmaxf(red[2][0], red[3][0]));
        bm = fmaxf(fmaxf(red[0][1], red[1][1]), fmaxf(red[2][1], red[3][1]));
        c4 = fmaxf(fmaxf(red[0][2], red[1][2]), fmaxf(red[2][2], red[3][2]));
        d4 = fmaxf(fmaxf(red[0][3], red[1][3]), fmaxf(red[2][3], red[3][3]));
    }
    const float tP_max = a, tG_max = bm;
    const float invP = rcpf(tP_max + 1e-8f);
    const float invG = rcpf(tG_max + 1e-8f);

    const int T = blockIdx.x * 256 + threadIdx.x;  // 2048 blocks cover NPIX/4
    if (T < NPIX / 4) {
        int idx = T * 4;
        int i = idx & (HW - 1);
        int y = i >> 9;
        int c = i & (W - 1);
        float4 ctr;
        float t[4], o[4];
        cross4(xP, idx, y, c, ctr, t);
#pragma unroll
        for (int k = 0; k < 4; k++) o[k] = sig_er(t[k] * invP);
        *(float4*)(yP + idx) = make_float4(o[0], o[1], o[2], o[3]);
        cross4(xG, idx, y, c, ctr, t);
#pragma unroll
        for (int k = 0; k < 4; k++) o[k] = sig_er(t[k] * invG);
        *(float4*)(yG + idx) = make_float4(o[0], o[1], o[2], o[3]);
    }
    if (blockIdx.x == 0 && threadIdx.x == 0) {
        *ymaxP = sig_er(tP_max * invP);
        *ymaxG = sig_er(tG_max * invG);
        *rmaxP = c4;
        *rmaxG = d4;
    }
}

// ---------------- final: sum 3*NBD partials, /B ------------------------------
__global__ __launch_bounds__(1024) void finalize_kernel(
    const float* __restrict__ PS, float* out) {
    int t = threadIdx.x;
    float s = PS[t] + PS[t + NBD] + PS[t + 2 * NBD];
    s = wave_sum(s);
    __shared__ float red[16];
    if ((t & 63) == 0) red[t >> 6] = s;
    __syncthreads();
    if (t == 0) {
        float tot = 0.0f;
#pragma unroll
        for (int i = 0; i < 16; i++) tot += red[i];
        out[0] = tot * (1.0f / (float)B);
    }
}

// ---------------- launch -----------------------------------------------------
extern "C" void kernel_launch(void* const* d_in, const int* in_sizes, int n_in,
                              void* d_out, int out_size, void* d_ws, size_t ws_size,
                              hipStream_t stream) {
    (void)in_sizes; (void)n_in; (void)out_size;
    const float* pred = (const float*)d_in[0];
    const float* gt   = (const float*)d_in[1];
    float* out = (float*)d_out;

    // ws (floats): S[64] | PM[4*NB1] | PS[3*NBD] | P1,G1,P2,G2 | CP (f16)
    float* S  = (float*)d_ws;
    float4* PM = (float4*)(S + 64);
    float* PS = S + 64 + 4 * NB1;
    float* P1 = PS + 3 * NBD;
    float* G1 = P1 + NPIX;
    float* P2 = G1 + NPIX;
    float* G2 = P2 + NPIX;
    __half* CP = (__half*)(G2 + NPIX);

    // merged path needs 12 f16 CP planes (48MB); fallback (R9 schedule) needs 4
    const size_t base_b = (size_t)(64 + 4 * NB1 + 3 * NBD) * 4 +
                          (size_t)4 * NPIX * 4;
    const bool merged = ws_size >= base_b + (size_t)12 * NPIX * 2;

    const dim3 b1(256), g1(NB1), gE(NPIX / 4 / 256);
    const dim3 b2(16, 16, 1);

    // erosion chain
    cross_max_both_kernel<<<g1, b1, 0, stream>>>(pred, gt, PM);
    erode_both_kernel<<<gE, b1, 0, stream>>>(pred, gt, PM, P1, G1,
                                             S + 1, S + 4, S + 0, S + 3);
    cross_max_both_kernel<<<g1, b1, 0, stream>>>(P1, G1, PM);
    erode_both_kernel<<<gE, b1, 0, stream>>>(P1, G1, PM, P2, G2,
                                             S + 2, S + 5, S + 12, S + 13);

    if (merged) {
        // all 3 levels in one cp dispatch (one tail) + one dil dispatch
        cp_quad_kernel<<<dim3(W / 16, H / 16, 3 * B), b2, 0, stream>>>(
            pred, gt, P1, G1, P2, G2, S, 0, 0, CP);
        dil_diff2_kernel<<<dim3(3 * NBD), b1, 0, stream>>>(CP, PS);
    } else {
        for (int lvl = 0; lvl < 3; lvl++) {
            cp_quad_kernel<<<dim3(W / 16, H / 16, B), b2, 0, stream>>>(
                pred, gt, P1, G1, P2, G2, S, lvl, lvl, CP);
            dil_diff2_kernel<<<dim3(NBD), b1, 0, stream>>>(CP, PS + lvl * NBD);
        }
    }

    finalize_kernel<<<1, 1024, 0, stream>>>(PS, out);
}

// Round 3
// 266.973 us; speedup vs baseline: 1.3218x; 1.1790x over previous
//
#include <hip/hip_runtime.h>
#include <hip/hip_fp16.h>
#include <cstdint>

// Problem constants (setup_inputs: B=8, H=W=512, num_erosions=2)
static constexpr int B = 8;
static constexpr int H = 512;
static constexpr int W = 512;
static constexpr int HW = H * W;
static constexpr int NPIX = B * HW;
static constexpr int NB1 = 1024;  // blocks for cross_max partials
static constexpr int NBD = 1024;  // blocks per dil_diff level

// cp_main tiling: interior = 16x32 tiles (2 px/thread), edge ring = 16x16
static constexpr int N_INT = 30 * 14;   // txB in [1,30], tyB in [1,14]
static constexpr int N_EDGE = 64 + 120; // 2 cols x 32 + 4 rows x 30
static constexpr int GRID_X = N_INT + N_EDGE;  // 604

// 10*log2(e): sigmoid(10*z) = 1/(1+2^(-CC*z))
static constexpr float CC = 14.4269504088896f;

// ---------------- helpers ----------------------------------------------------
// R14: interleaved CP records -> WRITE amplification fixed (419->49MB) but
//   dur unchanged => VALU-issue-bound. R15: f2 (P,G) packing via VOP3P ->
//   218us, VALUBusy 64%, occ 31% => now latency/overhead-bound (issue floor
//   ~85-140us). R16: amortize serial per-block cost: 2px/thread interior
//   (16x32 tiles, 1 barrier per 2 outputs), block-role split (branch-free
//   interior), pair-consts hoisted to setup kernel (dead PM region, -12
//   uniform exps/thread).
__device__ __forceinline__ float rcpf(float x) { return __builtin_amdgcn_rcpf(x); }
__device__ __forceinline__ float exp2f_n(float x) { return __builtin_amdgcn_exp2f(x); }

typedef __attribute__((ext_vector_type(2))) float f2;

__device__ __forceinline__ f2 mk2(float a, float b) { f2 r; r.x = a; r.y = b; return r; }
__device__ __forceinline__ f2 exp2_2(f2 v) {
    f2 r; r.x = exp2f_n(v.x); r.y = exp2f_n(v.y); return r;
}
__device__ __forceinline__ f2 rcp_2(f2 v) {
    f2 r; r.x = rcpf(v.x); r.y = rcpf(v.y); return r;
}
#if defined(__has_builtin)
#if __has_builtin(__builtin_elementwise_fma)
#define FMA2(a, b, c) __builtin_elementwise_fma((a), (b), (c))
#endif
#endif
#ifndef FMA2
__device__ __forceinline__ f2 fma2_(f2 a, f2 b, f2 c) {
    f2 r; r.x = fmaf(a.x, b.x, c.x); r.y = fmaf(a.y, b.y, c.y); return r;
}
#define FMA2(a, b, c) fma2_((a), (b), (c))
#endif

__device__ __forceinline__ float sig_cp(float x) {  // sigmoid(10(x-0.5))
    return rcpf(1.0f + exp2f_n(fmaf(x, -CC, 0.5f * CC)));
}
__device__ __forceinline__ float sig_er(float r) {  // sigmoid(10(r-0.7))
    return rcpf(1.0f + exp2f_n(fmaf(r, -CC, 0.7f * CC)));
}
// Shared-exp complement pair (R12): one exp per (direct, complement) pair.
// f2 lanes carry (P, G). negA = -(CC+m), s2m = 2^m per class per image.
__device__ __forceinline__ void pair_term2(f2 nc, f2 negA, f2 s2m,
                                           f2& sd, f2& sc) {
    const f2 CC2 = CC;
    const f2 one2 = 1.0f;
    f2 w = exp2_2(FMA2(nc, CC2, negA));
    sd += rcp_2(FMA2(w, s2m, one2));
    sc += w * rcp_2(w + s2m);
}
// plain direct-only sigmoid (padded edge phases), f2 lanes (P, G)
__device__ __forceinline__ void end_term2(f2 nc, f2& sd) {
    const f2 CC2 = CC;
    const f2 nCC2 = -CC;
    const f2 one2 = 1.0f;
    sd += rcp_2(one2 + exp2_2(FMA2(nc, CC2, nCC2)));
}
__device__ __forceinline__ float wave_max(float m) {
#pragma unroll
    for (int o = 32; o > 0; o >>= 1) m = fmaxf(m, __shfl_down(m, o, 64));
    return m;
}
__device__ __forceinline__ float wave_sum(float s) {
#pragma unroll
    for (int o = 32; o > 0; o >>= 1) s += __shfl_down(s, o, 64);
    return s;
}

// packed 4x f16 pixel record (planes interleaved)
union H4 {
    uint64_t u;
    __half2 h2[2];
    __half h[4];
};

// ---------------- row-sweep mask conv sums (f2: lanes = P,G) -----------------
struct NC2 {
    f2 n3[8], n4[8], n5[8], n6[7];
    f2 v;  // center value w[3][3]
};

template <int STRIDE>
__device__ __forceinline__ NC2 sweep2(const f2* rp) {
    NC2 o;
    f2 r2s, r3s, r4s;
    f2 cen0, cen1, cen2, cen3, cen4, cen5, cen6, cen7, cen8;
    {   // win row 0 = K6 row 0
        f2 c0 = rp[0], c1 = rp[1], c2 = rp[2], c3 = rp[3], c4 = rp[4], c5 = rp[5];
        f2 c45 = c4 + c5, c01 = c0 + c1;
        f2 S6 = (c01 + (c2 + c3)) + c45;
        o.n6[0] = c45; o.n6[1] = c01; o.n6[2] = S6; o.n6[3] = S6;
        o.n6[4] = S6;  o.n6[5] = S6;  o.n6[6] = S6;
    }
    rp += STRIDE;
    {   // win row 1 = K6 r1, K5 r0, K4 r0
        f2 c0 = rp[0], c1 = rp[1], c2 = rp[2], c3 = rp[3], c4 = rp[4], c5 = rp[5];
        f2 c45 = c4 + c5, c12 = c1 + c2, c34 = c3 + c4;
        f2 S4 = c12 + c34, S5 = S4 + c5;
        f2 c15 = c1 + c5, c05 = c0 + c5, c14 = c1 + c4;
        o.n6[0] += c5;  o.n6[1] += c0;  o.n6[2] += c05; o.n6[3] += c05;
        o.n6[4] += c0;  o.n6[5] += c5;  o.n6[6] += c05;
        o.n5[0] = c45; o.n5[1] = c12; o.n5[2] = S5; o.n5[3] = S5;
        o.n5[4] = S5;  o.n5[5] = S5;  o.n5[6] = S5; o.n5[7] = c15;
        o.n4[0] = c34; o.n4[1] = c12; o.n4[2] = S4; o.n4[3] = S4;
        o.n4[4] = c14; o.n4[5] = S4;  o.n4[6] = S4; o.n4[7] = S4;
    }
    rp += STRIDE;
    {   // win row 2 = K6 r2, K5 r1, K4 r1, K3 r0
        f2 c0 = rp[0], c1 = rp[1], c2 = rp[2], c3 = rp[3], c4 = rp[4], c5 = rp[5];
        f2 c05 = c0 + c5, c15 = c1 + c5, c14 = c1 + c4;
        r2s = (c2 + c3) + c4;
        cen0 = c2; cen1 = c3; cen2 = c4;
        o.n6[0] += c5;  o.n6[1] += c0;  o.n6[2] += c0;  o.n6[3] += c5;
        o.n6[4] += c0;  o.n6[5] += c5;  o.n6[6] += c05;
        o.n5[0] += c5;  o.n5[1] += c1;  o.n5[2] += c15; o.n5[3] += c15;
        o.n5[4] += c1;  o.n5[5] += c5;  o.n5[6] += c15; o.n5[7] += c15;
        o.n4[0] += c4;  o.n4[1] += c1;  o.n4[2] += c14; o.n4[3] += c14;
        o.n4[4] += c14; o.n4[5] += c4;  o.n4[6] += c14; o.n4[7] += c1;
    }
    rp += STRIDE;
    {   // win row 3 = K6 r3, K5 r2, K4 r2, K3 r1 (center row)
        f2 c0 = rp[0], c1 = rp[1], c2 = rp[2], c3 = rp[3], c4 = rp[4], c5 = rp[5];
        f2 c05 = c0 + c5, c15 = c1 + c5, c14 = c1 + c4;
        r3s = (c2 + c3) + c4;
        cen3 = c2; cen4 = c3; cen5 = c4;
        o.v = c3;
        o.n6[0] += c5;  o.n6[1] += c0;  o.n6[2] += c0;  o.n6[3] += c5;
        o.n6[4] += c0;  o.n6[5] += c5;  o.n6[6] += c05;
        o.n5[0] += c5;  o.n5[1] += c1;  o.n5[2] += c1;  o.n5[3] += c5;
        o.n5[4] += c1;  o.n5[5] += c5;  o.n5[6] += c15; o.n5[7] += c15;
        o.n4[0] += c14; o.n4[1] += c14; o.n4[2] += c4;  o.n4[3] += c1;
        o.n4[4] += c14; o.n4[5] += c4;  o.n4[6] += c14; o.n4[7] += c1;
    }
    rp += STRIDE;
    {   // win row 4 = K6 r4, K5 r3, K4 r3, K3 r2
        f2 c0 = rp[0], c1 = rp[1], c2 = rp[2], c3 = rp[3], c4 = rp[4], c5 = rp[5];
        f2 c05 = c0 + c5, c15 = c1 + c5, c12 = c1 + c2, c34 = c3 + c4;
        f2 S4 = c12 + c34, c14 = c1 + c4;
        r4s = (c2 + c3) + c4;
        cen6 = c2; cen7 = c3; cen8 = c4;
        o.n6[0] += c05; o.n6[1] += c05; o.n6[2] += c0;  o.n6[3] += c5;
        o.n6[4] += c0;  o.n6[5] += c5;  o.n6[6] += c05;
        o.n5[0] += c15; o.n5[1] += c15; o.n5[2] += c1;  o.n5[3] += c5;
        o.n5[4] += c1;  o.n5[5] += c5;  o.n5[6] += c15; o.n5[7] += c15;
        o.n4[0] += S4;  o.n4[1] += S4;  o.n4[2] += c34; o.n4[3] += c12;
        o.n4[4] += S4;  o.n4[5] += S4;  o.n4[6] += c14; o.n4[7] += S4;
    }
    rp += STRIDE;
    {   // win row 5 = K6 r5, K5 r4
        f2 c0 = rp[0], c1 = rp[1], c2 = rp[2], c3 = rp[3], c4 = rp[4], c5 = rp[5];
        f2 c45 = c4 + c5, c12 = c1 + c2;
        f2 t = c3 + c45, S5 = c12 + t, S6 = S5 + c0;
        f2 c01 = c0 + c1, c05 = c0 + c5, c15 = c1 + c5;
        o.n6[0] += S6;  o.n6[1] += S6;  o.n6[2] += c01; o.n6[3] += c45;
        o.n6[4] += S6;  o.n6[5] += S6;  o.n6[6] += c05;
        o.n5[0] += S5;  o.n5[1] += S5;  o.n5[2] += c12; o.n5[3] += c45;
        o.n5[4] += S5;  o.n5[5] += S5;  o.n5[6] += c15; o.n5[7] += S5;
    }
    // K3: all 8 masks = S33 - center - one distinct cell
    f2 S33 = (r2s + r3s) + r4s;
    f2 T = S33 - cen4;
    o.n3[0] = T - cen3; o.n3[1] = T - cen7; o.n3[2] = T - cen5; o.n3[3] = T - cen1;
    o.n3[4] = T - cen0; o.n3[5] = T - cen6; o.n3[6] = T - cen8; o.n3[7] = T - cen2;
    return o;
}

// class index per mask into per-class constants; counts {7,9,10,11,13,16}
__constant__ __device__ const int CI4[8] = {1, 1, 1, 1, 2, 2, 2, 2};
__constant__ __device__ const int CI5[8] = {3, 3, 3, 3, 4, 4, 4, 4};
__constant__ __device__ const int CI6[7] = {4, 4, 4, 4, 5, 5, 5};

// PAIR=true: negA[6] = -(CC+m_c), s2m[6] = 2^m_c (shared-exp pairs).
// PAIR=false: plain endsig on direct only (padded edge phases).
template <bool PAIR>
__device__ __forceinline__ void ssum_from_nc2(const NC2& a, const f2* negA,
                                              const f2* s2m, f2& sD, f2& sC) {
    f2 sd = 0.0f, sc = 0.0f;
#pragma unroll
    for (int k = 0; k < 8; k++) {
        if constexpr (PAIR) pair_term2(a.n3[k], negA[0], s2m[0], sd, sc);
        else end_term2(a.n3[k], sd);
    }
#pragma unroll
    for (int k = 0; k < 8; k++) {
        if constexpr (PAIR) pair_term2(a.n4[k], negA[CI4[k]], s2m[CI4[k]], sd, sc);
        else end_term2(a.n4[k], sd);
    }
#pragma unroll
    for (int k = 0; k < 8; k++) {
        if constexpr (PAIR) pair_term2(a.n5[k], negA[CI5[k]], s2m[CI5[k]], sd, sc);
        else end_term2(a.n5[k], sd);
    }
#pragma unroll
    for (int k = 0; k < 7; k++) {
        if constexpr (PAIR) pair_term2(a.n6[k], negA[CI6[k]], s2m[CI6[k]], sd, sc);
        else end_term2(a.n6[k], sd);
    }
    sD = sd;
    sC = sc;
}

// ---------------- setup: per-(lvl,class,img) pair constants ------------------
// CST layout (floats): lvl*24 + cls*2 + img -> negA; +12 -> s2m.
// Same op sequence as the old per-thread build => bit-identical constants.
__global__ void setup_consts_kernel(const float* __restrict__ S,
                                    float* __restrict__ CST) {
    int t = threadIdx.x;
    if (t < 36) {
        int lvl = t / 12, rem = t % 12, cls = rem >> 1, img = rem & 1;
        const float cntf[6] = {7.0f, 9.0f, 10.0f, 11.0f, 13.0f, 16.0f};
        float M = S[lvl + 3 * img];
        float cm = fmaf(cntf[cls] * M, CC, -CC);
        float m = 0.5f * (cm - CC);
        CST[lvl * 24 + cls * 2 + img] = -(CC + m);
        CST[lvl * 24 + 12 + cls * 2 + img] = exp2f_n(m);
    }
}

// ---------------- cp_main: interior 2px/thread + edge ring -------------------
// blockIdx.x < N_INT: interior 16x32 tile (txB=1+bx%30, tyB=1+bx/30),
//   branch-free pair path, 2 outputs/thread sharing one LDS window + barrier.
// else: 16x16 ring tile; fast pair path when window in-bounds, two-phase
//   padded path otherwise. z-slice -> (lvl = lvl_base + z>>3, b = z&7).
__global__ __launch_bounds__(256, 4) void cp_main_kernel(
    const float* __restrict__ x0P, const float* __restrict__ x0G,
    const float* __restrict__ x1P, const float* __restrict__ x1G,
    const float* __restrict__ x2P, const float* __restrict__ x2G,
    const float* __restrict__ S, const float* __restrict__ CST,
    int lvl_base, int plane_lvl0, __half* __restrict__ cp) {
    __shared__ f2 win[37][23];
    const int lvl = lvl_base + (blockIdx.z >> 3);
    const int b = blockIdx.z & 7;
    const float* xP = (lvl == 0) ? x0P : (lvl == 1) ? x1P : x2P;
    const float* xG = (lvl == 0) ? x0G : (lvl == 1) ? x1G : x2G;
    const float MP = S[lvl], MG = S[3 + lvl];
    __half* cpb = cp + (size_t)(4 * (lvl - plane_lvl0)) * NPIX;
    const int tid = threadIdx.y * 16 + threadIdx.x;
    const int ty = threadIdx.y, tx = threadIdx.x;
    const f2* cbase = (const f2*)(CST + lvl * 24);

    if (blockIdx.x < N_INT) {
        const int txB = 1 + (int)blockIdx.x % 30;
        const int tyB = 1 + (int)blockIdx.x / 30;
        const int ox0 = txB * 16, oy0 = tyB * 32;
        const float* pb = xP + b * HW + (oy0 - 3) * W + (ox0 - 3);
        const float* gb = xG + b * HW + (oy0 - 3) * W + (ox0 - 3);
        for (int i = tid; i < 37 * 21; i += 256) {
            int r = i / 21, c = i % 21;
            win[r][c] = mk2(pb[r * W + c], gb[r * W + c]);
        }
        __syncthreads();
        f2 negA[6], s2m[6];
#pragma unroll
        for (int c = 0; c < 6; c++) { negA[c] = cbase[c]; s2m[c] = cbase[6 + c]; }
        int o = b * HW + (oy0 + ty) * W + (ox0 + tx);
        {
            f2 sd, sc;
            NC2 a = sweep2<23>(&win[ty][tx]);
            ssum_from_nc2<true>(a, negA, s2m, sd, sc);
            H4 v;
            v.h[0] = __float2half(sig_cp(a.v.x * sd.x));
            v.h[1] = __float2half(sig_cp(a.v.y * sd.y));
            v.h[2] = __float2half(sig_cp((MP - a.v.x) * sc.x));
            v.h[3] = __float2half(sig_cp((MG - a.v.y) * sc.y));
            *(uint64_t*)(cpb + (size_t)o * 4) = v.u;
        }
        o += 16 * W;
        {
            f2 sd, sc;
            NC2 a = sweep2<23>(&win[ty + 16][tx]);
            ssum_from_nc2<true>(a, negA, s2m, sd, sc);
            H4 v;
            v.h[0] = __float2half(sig_cp(a.v.x * sd.x));
            v.h[1] = __float2half(sig_cp(a.v.y * sd.y));
            v.h[2] = __float2half(sig_cp((MP - a.v.x) * sc.x));
            v.h[3] = __float2half(sig_cp((MG - a.v.y) * sc.y));
            *(uint64_t*)(cpb + (size_t)o * 4) = v.u;
        }
    } else {
        const int e = (int)blockIdx.x - N_INT;
        int tx16, ty16;
        if (e < 64) {
            ty16 = e >> 1;
            tx16 = (e & 1) ? 31 : 0;
        } else {
            int e2 = e - 64;
            int r = e2 / 30;
            ty16 = (r == 0) ? 0 : (r == 1) ? 1 : (r == 2) ? 30 : 31;
            tx16 = 1 + e2 % 30;
        }
        const int ox0 = tx16 * 16, oy0 = ty16 * 16;
        const int o = b * HW + (oy0 + ty) * W + (ox0 + tx);
        const bool fastw = (tx16 >= 1) & (tx16 <= 30) & (ty16 >= 1) & (ty16 <= 30);
        if (fastw) {
            const float* pb = xP + b * HW + (oy0 - 3) * W + (ox0 - 3);
            const float* gb = xG + b * HW + (oy0 - 3) * W + (ox0 - 3);
            for (int i = tid; i < 21 * 21; i += 256) {
                int r = i / 21, c = i % 21;
                win[r][c] = mk2(pb[r * W + c], gb[r * W + c]);
            }
            __syncthreads();
            f2 negA[6], s2m[6], sd, sc;
#pragma unroll
            for (int c = 0; c < 6; c++) { negA[c] = cbase[c]; s2m[c] = cbase[6 + c]; }
            NC2 a = sweep2<23>(&win[ty][tx]);
            ssum_from_nc2<true>(a, negA, s2m, sd, sc);
            H4 v;
            v.h[0] = __float2half(sig_cp(a.v.x * sd.x));
            v.h[1] = __float2half(sig_cp(a.v.y * sd.y));
            v.h[2] = __float2half(sig_cp((MP - a.v.x) * sc.x));
            v.h[3] = __float2half(sig_cp((MG - a.v.y) * sc.y));
            *(uint64_t*)(cpb + (size_t)o * 4) = v.u;
        } else {
            const float* pb = xP + b * HW;
            const float* gb = xG + b * HW;
            // phase A: direct planes
            for (int i = tid; i < 21 * 21; i += 256) {
                int r = i / 21, c = i % 21;
                int pr = oy0 - 2 + r;  // padded coords (0..513 valid)
                int pc = ox0 - 2 + c;
                f2 v;
                if (pr < 0 || pr > H + 1 || pc < 0 || pc > W + 1) {
                    v = 0.0f;  // conv zero-pad
                } else if (pr == 0 || pr == H + 1 || pc == 0 || pc == W + 1) {
                    v = 1.0f;  // image 1-pad
                } else {
                    v = mk2(pb[(pr - 1) * W + (pc - 1)], gb[(pr - 1) * W + (pc - 1)]);
                }
                win[r][c] = v;
            }
            __syncthreads();
            f2 sd, sc, junk;
            NC2 a = sweep2<23>(&win[ty][tx]);
            ssum_from_nc2<false>(a, nullptr, nullptr, sd, junk);
            f2 vD = a.v;
            __half2* po = (__half2*)(cpb + (size_t)o * 4);
            po[0] = __halves2half2(__float2half(sig_cp(vD.x * sd.x)),
                                   __float2half(sig_cp(vD.y * sd.y)));
            __syncthreads();  // all reads of direct planes done
            // phase B: complement planes
            for (int i = tid; i < 21 * 21; i += 256) {
                int r = i / 21, c = i % 21;
                int pr = oy0 - 2 + r;
                int pc = ox0 - 2 + c;
                f2 v;
                if (pr < 0 || pr > H + 1 || pc < 0 || pc > W + 1) {
                    v = 0.0f;
                } else if (pr == 0 || pr == H + 1 || pc == 0 || pc == W + 1) {
                    v = 1.0f;
                } else {
                    v = mk2(MP - pb[(pr - 1) * W + (pc - 1)],
                            MG - gb[(pr - 1) * W + (pc - 1)]);
                }
                win[r][c] = v;
            }
            __syncthreads();
            NC2 ac = sweep2<23>(&win[ty][tx]);
            ssum_from_nc2<false>(ac, nullptr, nullptr, sc, junk);
            po[1] = __halves2half2(__float2half(sig_cp(ac.v.x * sc.x)),
                                   __float2half(sig_cp(ac.v.y * sc.y)));
        }
    }
}

// ---------------- dil_diff: 8 rows/thread, interleaved f16, multi-level ------
__device__ __forceinline__ float4 h4_add(float4 a, uint64_t u) {
    H4 v; v.u = u;
    float2 p0 = __half22float2(v.h2[0]);
    float2 p1 = __half22float2(v.h2[1]);
    a.x += p0.x; a.y += p0.y; a.z += p1.x; a.w += p1.y;
    return a;
}

__global__ __launch_bounds__(256) void dil_diff2_kernel(
    const __half* __restrict__ cp, float* __restrict__ partial) {
    const int plane_grp = blockIdx.x >> 10;  // NBD=1024 blocks per level
    const int r = blockIdx.x & (NBD - 1);
    const __half* cpb = cp + (size_t)(4 * plane_grp) * NPIX;
    const int T = r * 256 + threadIdx.x;
    const int x = T & (W - 1);
    const int g = T >> 9;
    const int y0 = (g & 63) << 3;  // 64 rowgroups of 8 rows
    const int b = g >> 6;
    const __half* pb = cpb + (size_t)b * HW * 4;

    float4 rs[10];
#pragma unroll
    for (int j = 0; j < 10; j++) {
        int yy = y0 - 1 + j;
        float4 acc = make_float4(0.0f, 0.0f, 0.0f, 0.0f);
        if (yy >= 0 && yy < H) {  // wave-uniform
            const __half* row = pb + (size_t)yy * (W * 4);
            if (x > 0)
                acc = h4_add(acc, *(const uint64_t*)(row + (size_t)(x - 1) * 4));
            acc = h4_add(acc, *(const uint64_t*)(row + (size_t)x * 4));
            if (x < W - 1)
                acc = h4_add(acc, *(const uint64_t*)(row + (size_t)(x + 1) * 4));
        }
        rs[j] = acc;
    }

    float s = 0.0f;
#pragma unroll
    for (int i = 0; i < 8; i++) {
        float s0 = (rs[i].x + rs[i + 1].x) + rs[i + 2].x;
        float s1 = (rs[i].y + rs[i + 1].y) + rs[i + 2].y;
        float s2 = (rs[i].z + rs[i + 1].z) + rs[i + 2].z;
        float s3 = (rs[i].w + rs[i + 1].w) + rs[i + 2].w;
        float d1 = fminf(s0, 1.0f) - fminf(s1, 1.0f);
        float d2 = fminf(s2, 1.0f) - fminf(s3, 1.0f);
        s += fmaf(d1, d1, d2 * d2);
    }
    s = wave_sum(s);
    __shared__ float red[4];
    int tid = threadIdx.x;
    if ((tid & 63) == 0) red[tid >> 6] = s;
    __syncthreads();
    if (tid == 0) partial[blockIdx.x] = (red[0] + red[1]) + (red[2] + red[3]);
}

// ---------------- cross-conv 4px/thread helper -------------------------------
__device__ __forceinline__ void cross4(const float* __restrict__ xp, int idx,
                                       int y, int c, float4& ctr, float t[4]) {
    const float4* v = (const float4*)(xp + idx);
    ctr = v[0];
    float4 up = (y > 0) ? *(const float4*)(xp + idx - W)
                        : make_float4(0, 0, 0, 0);
    float4 dn = (y < H - 1) ? *(const float4*)(xp + idx + W)
                            : make_float4(0, 0, 0, 0);
    float lf = (c > 0) ? xp[idx - 1] : 0.0f;
    float rt = (c < W - 4) ? xp[idx + 4] : 0.0f;
    t[0] = (up.x + dn.x) + (lf + ctr.y);
    t[1] = (up.y + dn.y) + (ctr.x + ctr.z);
    t[2] = (up.z + dn.z) + (ctr.y + ctr.w);
    t[3] = (up.w + dn.w) + (ctr.z + rt);
}

// ---------------- erosion: cross-conv max pass -> float4 partial/block -------
__global__ __launch_bounds__(256) void cross_max_both_kernel(
    const float* __restrict__ xP, const float* __restrict__ xG,
    float4* __restrict__ partial) {
    float mtP = 0, mtG = 0, mrP = 0, mrG = 0;
    for (int T = blockIdx.x * 256 + threadIdx.x; T < NPIX / 4; T += NB1 * 256) {
        int idx = T * 4;
        int i = idx & (HW - 1);
        int y = i >> 9;
        int c = i & (W - 1);
        float4 ctr;
        float t[4];
        cross4(xP, idx, y, c, ctr, t);
        mtP = fmaxf(mtP, fmaxf(fmaxf(t[0], t[1]), fmaxf(t[2], t[3])));
        mrP = fmaxf(mrP, fmaxf(fmaxf(ctr.x, ctr.y), fmaxf(ctr.z, ctr.w)));
        cross4(xG, idx, y, c, ctr, t);
        mtG = fmaxf(mtG, fmaxf(fmaxf(t[0], t[1]), fmaxf(t[2], t[3])));
        mrG = fmaxf(mrG, fmaxf(fmaxf(ctr.x, ctr.y), fmaxf(ctr.z, ctr.w)));
    }
    mtP = wave_max(mtP); mtG = wave_max(mtG);
    mrP = wave_max(mrP); mrG = wave_max(mrG);
    __shared__ float red[4][4];
    int tid = threadIdx.x;
    if ((tid & 63) == 0) {
        int w = tid >> 6;
        red[w][0] = mtP; red[w][1] = mtG; red[w][2] = mrP; red[w][3] = mrG;
    }
    __syncthreads();
    if (tid == 0) {
        float4 r;
        r.x = fmaxf(fmaxf(red[0][0], red[1][0]), fmaxf(red[2][0], red[3][0]));
        r.y = fmaxf(fmaxf(red[0][1], red[1][1]), fmaxf(red[2][1], red[3][1]));
        r.z = fmaxf(fmaxf(red[0][2], red[1][2]), fmaxf(red[2][2], red[3][2]));
        r.w = fmaxf(fmaxf(red[0][3], red[1][3]), fmaxf(red[2][3], red[3][3]));
        partial[blockIdx.x] = r;
    }
}

// ---------------- erosion: fused PM-reduce + cross conv + normalize ----------
__global__ __launch_bounds__(256) void erode_both_kernel(
    const float* __restrict__ xP, const float* __restrict__ xG,
    const float4* __restrict__ PM,
    float* __restrict__ yP, float* __restrict__ yG,
    float* ymaxP, float* ymaxG, float* rmaxP, float* rmaxG) {
    // redundant per-block PM reduce (16KB, L2-resident)
    float a = 0, bm = 0, c4 = 0, d4 = 0;
    {
        int t = threadIdx.x;
#pragma unroll
        for (int k = 0; k < NB1 / 256; k++) {
            float4 p = PM[t + k * 256];
            a = fmaxf(a, p.x); bm = fmaxf(bm, p.y);
            c4 = fmaxf(c4, p.z); d4 = fmaxf(d4, p.w);
        }
        a = wave_max(a); bm = wave_max(bm); c4 = wave_max(c4); d4 = wave_max(d4);
        __shared__ float red[4][4];
        if ((t & 63) == 0) {
            int w = t >> 6;
            red[w][0] = a; red[w][1] = bm; red[w][2] = c4; red[w][3] = d4;
        }
        __syncthreads();
        a  = fmaxf(fmaxf(red[0][0], red[1][0]), fmaxf(red[2][0], red[3][0]));
        bm = fmaxf(fmaxf(red[0][1], red[1][1]), fmaxf(red[2][1], red[3][1]));
        c4 = fmaxf(fmaxf(red[0][2], red[1][2]), fmaxf(red[2][2], red[3][2]));
        d4 = fmaxf(fmaxf(red[0][3], red[1][3]), fmaxf(red[2][3], red[3][3]));
    }
    const float tP_max = a, tG_max = bm;
    const float invP = rcpf(tP_max + 1e-8f);
    const float invG = rcpf(tG_max + 1e-8f);

    const int T = blockIdx.x * 256 + threadIdx.x;  // 2048 blocks cover NPIX/4
    if (T < NPIX / 4) {
        int idx = T * 4;
        int i = idx & (HW - 1);
        int y = i >> 9;
        int c = i & (W - 1);
        float4 ctr;
        float t[4], o[4];
        cross4(xP, idx, y, c, ctr, t);
#pragma unroll
        for (int k = 0; k < 4; k++) o[k] = sig_er(t[k] * invP);
        *(float4*)(yP + idx) = make_float4(o[0], o[1], o[2], o[3]);
        cross4(xG, idx, y, c, ctr, t);
#pragma unroll
        for (int k = 0; k < 4; k++) o[k] = sig_er(t[k] * invG);
        *(float4*)(yG + idx) = make_float4(o[0], o[1], o[2], o[3]);
    }
    if (blockIdx.x == 0 && threadIdx.x == 0) {
        *ymaxP = sig_er(tP_max * invP);
        *ymaxG = sig_er(tG_max * invG);
        *rmaxP = c4;
        *rmaxG = d4;
    }
}

// ---------------- final: sum 3*NBD partials, /B ------------------------------
__global__ __launch_bounds__(1024) void finalize_kernel(
    const float* __restrict__ PS, float* out) {
    int t = threadIdx.x;
    float s = PS[t] + PS[t + NBD] + PS[t + 2 * NBD];
    s = wave_sum(s);
    __shared__ float red[16];
    if ((t & 63) == 0) red[t >> 6] = s;
    __syncthreads();
    if (t == 0) {
        float tot = 0.0f;
#pragma unroll
        for (int i = 0; i < 16; i++) tot += red[i];
        out[0] = tot * (1.0f / (float)B);
    }
}

// ---------------- launch -----------------------------------------------------
extern "C" void kernel_launch(void* const* d_in, const int* in_sizes, int n_in,
                              void* d_out, int out_size, void* d_ws, size_t ws_size,
                              hipStream_t stream) {
    (void)in_sizes; (void)n_in; (void)out_size;
    const float* pred = (const float*)d_in[0];
    const float* gt   = (const float*)d_in[1];
    float* out = (float*)d_out;

    // ws (floats): S[64] | PM[4*NB1] | PS[3*NBD] | P1,G1,P2,G2 | CP (f16)
    // CST (72 floats) aliases the PM region (dead after erode2).
    float* S  = (float*)d_ws;
    float4* PM = (float4*)(S + 64);
    float* CST = S + 64;
    float* PS = S + 64 + 4 * NB1;
    float* P1 = PS + 3 * NBD;
    float* G1 = P1 + NPIX;
    float* P2 = G1 + NPIX;
    float* G2 = P2 + NPIX;
    __half* CP = (__half*)(G2 + NPIX);

    // merged path needs 12 f16 CP planes (48MB); fallback needs 4
    const size_t base_b = (size_t)(64 + 4 * NB1 + 3 * NBD) * 4 +
                          (size_t)4 * NPIX * 4;
    const bool merged = ws_size >= base_b + (size_t)12 * NPIX * 2;

    const dim3 b1(256), g1(NB1), gE(NPIX / 4 / 256);
    const dim3 b2(16, 16, 1);

    // erosion chain
    cross_max_both_kernel<<<g1, b1, 0, stream>>>(pred, gt, PM);
    erode_both_kernel<<<gE, b1, 0, stream>>>(pred, gt, PM, P1, G1,
                                             S + 1, S + 4, S + 0, S + 3);
    cross_max_both_kernel<<<g1, b1, 0, stream>>>(P1, G1, PM);
    erode_both_kernel<<<gE, b1, 0, stream>>>(P1, G1, PM, P2, G2,
                                             S + 2, S + 5, S + 12, S + 13);
    setup_consts_kernel<<<1, 64, 0, stream>>>(S, CST);

    if (merged) {
        // all 3 levels in one cp dispatch (one tail) + one dil dispatch
        cp_main_kernel<<<dim3(GRID_X, 1, 3 * B), b2, 0, stream>>>(
            pred, gt, P1, G1, P2, G2, S, CST, 0, 0, CP);
        dil_diff2_kernel<<<dim3(3 * NBD), b1, 0, stream>>>(CP, PS);
    } else {
        for (int lvl = 0; lvl < 3; lvl++) {
            cp_main_kernel<<<dim3(GRID_X, 1, B), b2, 0, stream>>>(
                pred, gt, P1, G1, P2, G2, S, CST, lvl, lvl, CP);
            dil_diff2_kernel<<<dim3(NBD), b1, 0, stream>>>(CP, PS + lvl * NBD);
        }
    }

    finalize_kernel<<<1, 1024, 0, stream>>>(PS, out);
}